// Round 1
// baseline (286.257 us; speedup 1.0000x reference)
//
#include <hip/hip_runtime.h>
#include <cstdint>
#include <cstddef>

typedef __bf16 bf16x8 __attribute__((ext_vector_type(8)));
typedef float f32x4 __attribute__((ext_vector_type(4)));
typedef unsigned short ushort8 __attribute__((ext_vector_type(8)));

#define OUT_DIM 4096
#define IN_DIM 4096
#define BM 128
#define BN 128
#define BK 64

// ---------------- helpers ----------------

__device__ __forceinline__ unsigned short f2bf(float f) {
  // round-to-nearest-even f32 -> bf16 (inputs are finite)
  unsigned u = __float_as_uint(f);
  return (unsigned short)((u + 0x7FFFu + ((u >> 16) & 1u)) >> 16);
}

__device__ __forceinline__ void async_copy16(const void* g, void* l) {
  // global -> LDS direct copy, 16B per lane. LDS dest is wave-uniform base +
  // lane*16 (guide §5) — callers pass a wave-uniform LDS base.
  __builtin_amdgcn_global_load_lds(
      (const __attribute__((address_space(1))) unsigned int*)g,
      (__attribute__((address_space(3))) unsigned int*)l, 16, 0, 0);
}

// ---------------- weight build ----------------

// one thread = 4 packed bytes -> 8 fp32 weights. grid*block == OUT*IN/2/4 exactly.
__global__ __launch_bounds__(256) void dequant_kernel(
    const int* __restrict__ packed, const float* __restrict__ scales,
    float* __restrict__ wf) {
  int idx = blockIdx.x * 256 + threadIdx.x;
  int4 p = reinterpret_cast<const int4*>(packed)[idx];
  int row = idx >> 9;  // (IN/2)/4 = 512 int4-chunks per row
  float s = scales[row];
  float4 o0, o1;
  o0.x = (float)((p.x & 15) - 8) * s;
  o0.y = (float)(((p.x >> 4) & 15) - 8) * s;
  o0.z = (float)((p.y & 15) - 8) * s;
  o0.w = (float)(((p.y >> 4) & 15) - 8) * s;
  o1.x = (float)((p.z & 15) - 8) * s;
  o1.y = (float)(((p.z >> 4) & 15) - 8) * s;
  o1.z = (float)((p.w & 15) - 8) * s;
  o1.w = (float)(((p.w >> 4) & 15) - 8) * s;
  reinterpret_cast<float4*>(wf)[idx * 2] = o0;
  reinterpret_cast<float4*>(wf)[idx * 2 + 1] = o1;
}

__global__ __launch_bounds__(256) void scatter_kernel(
    const float* __restrict__ vals, const int* __restrict__ rows,
    const int* __restrict__ cols, float* __restrict__ wf, int nnz) {
  int i = blockIdx.x * 256 + threadIdx.x;
  if (i < nnz) {
    atomicAdd(&wf[(size_t)rows[i] * IN_DIM + cols[i]], vals[i]);
  }
}

// fp32 -> bf16 bits, 8 elements per thread. grid*block*8 == element count exactly.
__global__ __launch_bounds__(256) void cvt_kernel(
    const float* __restrict__ in, unsigned short* __restrict__ out) {
  int i = blockIdx.x * 256 + threadIdx.x;
  float4 a = reinterpret_cast<const float4*>(in)[2 * i];
  float4 b = reinterpret_cast<const float4*>(in)[2 * i + 1];
  ushort8 o;
  o[0] = f2bf(a.x); o[1] = f2bf(a.y); o[2] = f2bf(a.z); o[3] = f2bf(a.w);
  o[4] = f2bf(b.x); o[5] = f2bf(b.y); o[6] = f2bf(b.z); o[7] = f2bf(b.w);
  *reinterpret_cast<ushort8*>(&out[(size_t)i * 8]) = o;
}

// ---------------- GEMM: C[N][O] = A[N][K] * B[O][K]^T  (bf16 in, fp32 out) ---

__global__ __launch_bounds__(256) void gemm_bt_kernel(
    const unsigned short* __restrict__ A,  // [4096][4096] bf16 bits (x)
    const unsigned short* __restrict__ B,  // [4096][4096] bf16 bits (W)
    float* __restrict__ C) {               // [4096][4096] fp32
  __shared__ __align__(16) unsigned short As[BM * BK];
  __shared__ __align__(16) unsigned short Bs[BN * BK];

  const int tid = threadIdx.x;
  const int wave = tid >> 6;
  const int lane = tid & 63;
  const int wm = wave >> 1, wn = wave & 1;   // 2x2 wave grid, 64x64 out each
  const int m0 = blockIdx.y * BM, n0 = blockIdx.x * BN;
  const int lrow = lane & 15, lk = lane >> 4;

  f32x4 acc[4][4];
#pragma unroll
  for (int mi = 0; mi < 4; ++mi)
#pragma unroll
    for (int ni = 0; ni < 4; ++ni)
      acc[mi][ni] = (f32x4){0.f, 0.f, 0.f, 0.f};

  for (int k0 = 0; k0 < IN_DIM; k0 += BK) {
    // stage A tile: 128x64 bf16 = 1024 chunks of 16B; LDS layout linear
    // row-major [128][64] (chunk c -> row c>>3, k (c&7)*8) — required by
    // global_load_lds (base + lane*16, no per-lane scatter).
#pragma unroll
    for (int it = 0; it < 4; ++it) {
      int chunk = it * 256 + tid;
      int row = chunk >> 3, kc = chunk & 7;
      async_copy16(&A[(size_t)(m0 + row) * IN_DIM + k0 + kc * 8],
                   &As[(it * 256 + wave * 64) * 8]);
    }
#pragma unroll
    for (int it = 0; it < 4; ++it) {
      int chunk = it * 256 + tid;
      int row = chunk >> 3, kc = chunk & 7;
      async_copy16(&B[(size_t)(n0 + row) * IN_DIM + k0 + kc * 8],
                   &Bs[(it * 256 + wave * 64) * 8]);
    }
    __syncthreads();  // compiler emits vmcnt(0) drain before s_barrier

#pragma unroll
    for (int ks = 0; ks < 2; ++ks) {
      bf16x8 af[4], bfr[4];
#pragma unroll
      for (int i = 0; i < 4; ++i)
        af[i] = *reinterpret_cast<const bf16x8*>(
            &As[(wm * 64 + i * 16 + lrow) * BK + ks * 32 + lk * 8]);
#pragma unroll
      for (int i = 0; i < 4; ++i)
        bfr[i] = *reinterpret_cast<const bf16x8*>(
            &Bs[(wn * 64 + i * 16 + lrow) * BK + ks * 32 + lk * 8]);
#pragma unroll
      for (int mi = 0; mi < 4; ++mi)
#pragma unroll
        for (int ni = 0; ni < 4; ++ni)
          acc[mi][ni] = __builtin_amdgcn_mfma_f32_16x16x32_bf16(
              af[mi], bfr[ni], acc[mi][ni], 0, 0, 0);
    }
    __syncthreads();
  }

  // epilogue: D mapping col=lane&15, row=(lane>>4)*4+reg (m89-verified)
#pragma unroll
  for (int mi = 0; mi < 4; ++mi)
#pragma unroll
    for (int ni = 0; ni < 4; ++ni) {
      int m = m0 + wm * 64 + mi * 16 + lk * 4;
      int n = n0 + wn * 64 + ni * 16 + lrow;
      float* cp = &C[(size_t)m * OUT_DIM + n];
#pragma unroll
      for (int r = 0; r < 4; ++r)
        cp[(size_t)r * OUT_DIM] = acc[mi][ni][r];
    }
}

// ---------------- launch ----------------

extern "C" void kernel_launch(void* const* d_in, const int* in_sizes, int n_in,
                              void* d_out, int out_size, void* d_ws, size_t ws_size,
                              hipStream_t stream) {
  const float* x       = (const float*)d_in[0];  // [2,2048,4096] fp32
  const int*   packed  = (const int*)d_in[1];    // [4096,2048] int32 (1 byte each)
  const float* scales  = (const float*)d_in[2];  // [4096,1]
  const float* vals    = (const float*)d_in[3];  // [NNZ]
  const int*   rows    = (const int*)d_in[4];    // [NNZ]
  const int*   cols    = (const int*)d_in[5];    // [NNZ]
  float* out = (float*)d_out;                    // [4096,4096] fp32

  const int nnz = in_sizes[3];

  // ws layout: [0,32MB) W bf16 | [32,64MB) X bf16 | [64,128MB) W fp32 scratch
  char* ws = (char*)d_ws;
  const size_t MB = 1024 * 1024;
  unsigned short* Wb = (unsigned short*)ws;
  unsigned short* Xb = (unsigned short*)(ws + 32 * MB);
  float*          Wf = (float*)(ws + 64 * MB);

  // 1) dequant int4 -> fp32 W   (4096*2048 bytes / 4 per thread = 8192 blocks)
  dequant_kernel<<<8192, 256, 0, stream>>>(packed, scales, Wf);
  // 2) scatter sparse outliers (ALPHA = 1.0), duplicates accumulate
  scatter_kernel<<<(nnz + 255) / 256, 256, 0, stream>>>(vals, rows, cols, Wf, nnz);
  // 3) convert W and x to bf16 (16.7M elems each / 8 per thread = 8192 blocks)
  cvt_kernel<<<8192, 256, 0, stream>>>(Wf, Wb);
  cvt_kernel<<<8192, 256, 0, stream>>>(x, Xb);
  // 4) bf16 MFMA GEMM: out = Xb (4096x4096) * Wb^T
  gemm_bt_kernel<<<dim3(32, 32), 256, 0, stream>>>(Xb, Wb, out);
}

// Round 2
// 222.339 us; speedup vs baseline: 1.2875x; 1.2875x over previous
//
#include <hip/hip_runtime.h>
#include <cstdint>
#include <cstddef>

typedef __bf16 bf16x8 __attribute__((ext_vector_type(8)));
typedef float f32x4 __attribute__((ext_vector_type(4)));
typedef unsigned short ushort8 __attribute__((ext_vector_type(8)));

#define OUT_DIM 4096
#define IN_DIM 4096
#define NT 64  // K tiles of 64

// ---------------- helpers ----------------

__device__ __forceinline__ unsigned short f2bf(float f) {
  unsigned u = __float_as_uint(f);
  return (unsigned short)((u + 0x7FFFu + ((u >> 16) & 1u)) >> 16);
}

__device__ __forceinline__ void async_copy16(const void* g, void* l) {
  __builtin_amdgcn_global_load_lds(
      (const __attribute__((address_space(1))) unsigned int*)g,
      (__attribute__((address_space(3))) unsigned int*)l, 16, 0, 0);
}

// ---------------- weight build ----------------

__global__ __launch_bounds__(256) void scatter_kernel(
    const float* __restrict__ vals, const int* __restrict__ rows,
    const int* __restrict__ cols, float* __restrict__ delta, int nnz) {
  int i = blockIdx.x * 256 + threadIdx.x;
  if (i < nnz) {
    atomicAdd(&delta[(size_t)rows[i] * IN_DIM + cols[i]], vals[i]);
  }
}

// fused: int4 dequant + outlier delta add + round to bf16. 8 weights/thread.
__global__ __launch_bounds__(256) void dequant_fused_kernel(
    const int* __restrict__ packed, const float* __restrict__ scales,
    const float* __restrict__ delta, unsigned short* __restrict__ wb) {
  int idx = blockIdx.x * 256 + threadIdx.x;  // 4 packed int32 bytes -> 8 weights
  int4 p = reinterpret_cast<const int4*>(packed)[idx];
  float s = scales[idx >> 9];  // 512 int4-groups per row
  float4 d0 = reinterpret_cast<const float4*>(delta)[idx * 2];
  float4 d1 = reinterpret_cast<const float4*>(delta)[idx * 2 + 1];
  ushort8 o;
  o[0] = f2bf((float)((p.x & 15) - 8) * s + d0.x);
  o[1] = f2bf((float)(((p.x >> 4) & 15) - 8) * s + d0.y);
  o[2] = f2bf((float)((p.y & 15) - 8) * s + d0.z);
  o[3] = f2bf((float)(((p.y >> 4) & 15) - 8) * s + d0.w);
  o[4] = f2bf((float)((p.z & 15) - 8) * s + d1.x);
  o[5] = f2bf((float)(((p.z >> 4) & 15) - 8) * s + d1.y);
  o[6] = f2bf((float)((p.w & 15) - 8) * s + d1.z);
  o[7] = f2bf((float)(((p.w >> 4) & 15) - 8) * s + d1.w);
  *reinterpret_cast<ushort8*>(&wb[(size_t)idx * 8]) = o;
}

__global__ __launch_bounds__(256) void cvt_kernel(
    const float* __restrict__ in, unsigned short* __restrict__ out) {
  int i = blockIdx.x * 256 + threadIdx.x;
  float4 a = reinterpret_cast<const float4*>(in)[2 * i];
  float4 b = reinterpret_cast<const float4*>(in)[2 * i + 1];
  ushort8 o;
  o[0] = f2bf(a.x); o[1] = f2bf(a.y); o[2] = f2bf(a.z); o[3] = f2bf(a.w);
  o[4] = f2bf(b.x); o[5] = f2bf(b.y); o[6] = f2bf(b.z); o[7] = f2bf(b.w);
  *reinterpret_cast<ushort8*>(&out[(size_t)i * 8]) = o;
}

// ---------------- GEMM: C[N][O] = A[N][K] * B[O][K]^T, 256x256 tile, -------
// 8 waves, deep pipeline: k-half-major slabs, counted vmcnt, setprio.
// Slab = [256 rows][32 k] bf16 = 16KB; 8 slabs: [buf][op(A/B)][kh].
// Ledger (tile t in buf t%2): P1(mh0,ks0) issues A1(t+1)->buf^1;
// P2(mh1,ks0) issues B1(t+1)->buf^1, vmcnt(8); P3(mh0,ks1) issues
// A0(t+2)->buf; P4(mh1,ks1) issues B0(t+2)->buf, vmcnt(8).
// Every issue targets a slot whose last ds_read finished before a prior
// barrier; every ds_read covered by a prior vmcnt(8)+barrier (8 newer loads
// = exactly the 4 slabs issued since the needed one).

#define SLABOFF(buf, op, kh) ((((buf) * 4) + ((op) * 2) + (kh)) * 8192)

#define STAGE(buf, op, kh, kt)                                              \
  do {                                                                      \
    const unsigned short* g_ = ((op) ? gB : gA) + (kt) * 64 + (kh) * 32;    \
    unsigned short* l_ = (unsigned short*)lds + SLABOFF(buf, op, kh) + wave * 512; \
    async_copy16(g_, l_);                                                   \
    async_copy16(g_ + 128 * IN_DIM, l_ + 4096);                             \
  } while (0)

#define MFMA_ __builtin_amdgcn_mfma_f32_16x16x32_bf16

#define PHASE(BUF, KS, MH, READB, STAGEST, DOWAIT)                          \
  do {                                                                      \
    const unsigned short* as_ = (const unsigned short*)lds + SLABOFF(BUF, 0, KS); \
    bf16x8 a0_ = *(const bf16x8*)(as_ + offA[(MH) * 4 + 0]);                \
    bf16x8 a1_ = *(const bf16x8*)(as_ + offA[(MH) * 4 + 1]);                \
    bf16x8 a2_ = *(const bf16x8*)(as_ + offA[(MH) * 4 + 2]);                \
    bf16x8 a3_ = *(const bf16x8*)(as_ + offA[(MH) * 4 + 3]);                \
    if (READB) {                                                            \
      const unsigned short* bs_ = (const unsigned short*)lds + SLABOFF(BUF, 1, KS); \
      bB0 = *(const bf16x8*)(bs_ + offB[0]);                                \
      bB1 = *(const bf16x8*)(bs_ + offB[1]);                                \
      bB2 = *(const bf16x8*)(bs_ + offB[2]);                                \
      bB3 = *(const bf16x8*)(bs_ + offB[3]);                                \
    }                                                                       \
    STAGEST;                                                                \
    if (DOWAIT) asm volatile("s_waitcnt vmcnt(8)" ::: "memory");            \
    __builtin_amdgcn_s_barrier();                                           \
    asm volatile("s_waitcnt lgkmcnt(0)" ::: "memory");                      \
    __builtin_amdgcn_sched_barrier(0);                                      \
    __builtin_amdgcn_s_setprio(1);                                          \
    acc[(MH) * 4 + 0][0] = MFMA_(a0_, bB0, acc[(MH) * 4 + 0][0], 0, 0, 0);  \
    acc[(MH) * 4 + 0][1] = MFMA_(a0_, bB1, acc[(MH) * 4 + 0][1], 0, 0, 0);  \
    acc[(MH) * 4 + 0][2] = MFMA_(a0_, bB2, acc[(MH) * 4 + 0][2], 0, 0, 0);  \
    acc[(MH) * 4 + 0][3] = MFMA_(a0_, bB3, acc[(MH) * 4 + 0][3], 0, 0, 0);  \
    acc[(MH) * 4 + 1][0] = MFMA_(a1_, bB0, acc[(MH) * 4 + 1][0], 0, 0, 0);  \
    acc[(MH) * 4 + 1][1] = MFMA_(a1_, bB1, acc[(MH) * 4 + 1][1], 0, 0, 0);  \
    acc[(MH) * 4 + 1][2] = MFMA_(a1_, bB2, acc[(MH) * 4 + 1][2], 0, 0, 0);  \
    acc[(MH) * 4 + 1][3] = MFMA_(a1_, bB3, acc[(MH) * 4 + 1][3], 0, 0, 0);  \
    acc[(MH) * 4 + 2][0] = MFMA_(a2_, bB0, acc[(MH) * 4 + 2][0], 0, 0, 0);  \
    acc[(MH) * 4 + 2][1] = MFMA_(a2_, bB1, acc[(MH) * 4 + 2][1], 0, 0, 0);  \
    acc[(MH) * 4 + 2][2] = MFMA_(a2_, bB2, acc[(MH) * 4 + 2][2], 0, 0, 0);  \
    acc[(MH) * 4 + 2][3] = MFMA_(a2_, bB3, acc[(MH) * 4 + 2][3], 0, 0, 0);  \
    acc[(MH) * 4 + 3][0] = MFMA_(a3_, bB0, acc[(MH) * 4 + 3][0], 0, 0, 0);  \
    acc[(MH) * 4 + 3][1] = MFMA_(a3_, bB1, acc[(MH) * 4 + 3][1], 0, 0, 0);  \
    acc[(MH) * 4 + 3][2] = MFMA_(a3_, bB2, acc[(MH) * 4 + 3][2], 0, 0, 0);  \
    acc[(MH) * 4 + 3][3] = MFMA_(a3_, bB3, acc[(MH) * 4 + 3][3], 0, 0, 0);  \
    __builtin_amdgcn_s_setprio(0);                                          \
    __builtin_amdgcn_s_barrier();                                           \
  } while (0)

#define MINC(x) ((x) < NT ? (x) : (NT - 1))

#define TILE(BUF, t)                                                        \
  do {                                                                      \
    PHASE(BUF, 0, 0, true, STAGE(1 - (BUF), 0, 1, MINC((t) + 1)), false);   \
    PHASE(BUF, 0, 1, false, STAGE(1 - (BUF), 1, 1, MINC((t) + 1)), true);   \
    PHASE(BUF, 1, 0, true, STAGE(BUF, 0, 0, MINC((t) + 2)), false);         \
    PHASE(BUF, 1, 1, false, STAGE(BUF, 1, 0, MINC((t) + 2)), true);         \
  } while (0)

__global__ __launch_bounds__(512, 2) void gemm_kernel(
    const unsigned short* __restrict__ A,  // [4096][4096] bf16 (x)
    const unsigned short* __restrict__ B,  // [4096][4096] bf16 (W)
    float* __restrict__ C) {               // [4096][4096] fp32
  __shared__ __align__(16) unsigned short lds[65536];  // 128 KiB

  // 4x8 (bm x bn) super-tile per XCD for L2 locality; 256%8==0 -> bijective
  const int bid = blockIdx.x;
  const int xcd = bid & 7, i_ = bid >> 3;
  const int bm = (xcd >> 1) * 4 + (i_ >> 3);
  const int bn = (xcd & 1) * 8 + (i_ & 7);
  const int m0 = bm * 256, n0 = bn * 256;

  const int tid = threadIdx.x;
  const int wave = tid >> 6, lane = tid & 63;
  const int wm = wave >> 2, wn = wave & 3;  // 2M x 4N wave grid
  const int lrow = lane & 15, lk = lane >> 4;

  // staging: chunk0 = tid -> (row=tid>>2, slot=tid&3); chunk1 = +128 rows
  const int r0 = tid >> 2, s0 = tid & 3;
  const unsigned short* gA = A + (size_t)(m0 + r0) * IN_DIM + s0 * 8;
  const unsigned short* gB = B + (size_t)(n0 + r0) * IN_DIM + s0 * 8;

  // frag read offsets (ushort units) within a [256][32] slab
  int offA[8], offB[4];
#pragma unroll
  for (int i = 0; i < 8; ++i) offA[i] = (wm * 128 + i * 16 + lrow) * 32 + lk * 8;
#pragma unroll
  for (int i = 0; i < 4; ++i) offB[i] = (wn * 64 + i * 16 + lrow) * 32 + lk * 8;

  f32x4 acc[8][4];
#pragma unroll
  for (int mi = 0; mi < 8; ++mi)
#pragma unroll
    for (int ni = 0; ni < 4; ++ni) acc[mi][ni] = (f32x4){0.f, 0.f, 0.f, 0.f};

  // prologue: A0(0) B0(0) A1(0) B1(0) -> buf0; A0(1) B0(1) -> buf1.
  // empty-asm separators pin issue order (vmcnt counts issue order).
  STAGE(0, 0, 0, 0); STAGE(0, 1, 0, 0);
  asm volatile("" ::: "memory");
  STAGE(0, 0, 1, 0); STAGE(0, 1, 1, 0);
  asm volatile("" ::: "memory");
  STAGE(1, 0, 0, 1); STAGE(1, 1, 0, 1);
  asm volatile("s_waitcnt vmcnt(8)" ::: "memory");  // A0(0),B0(0) complete
  __builtin_amdgcn_s_barrier();

  bf16x8 bB0, bB1, bB2, bB3;
#pragma unroll 1
  for (int p = 0; p < NT / 2; ++p) {
    const int te = 2 * p;
    TILE(0, te);
    TILE(1, te + 1);
  }
  asm volatile("s_waitcnt vmcnt(0)" ::: "memory");  // drain DMA before endpgm

  // epilogue: D mapping col=lane&15, row=(lane>>4)*4+reg
#pragma unroll
  for (int mi = 0; mi < 8; ++mi)
#pragma unroll
    for (int ni = 0; ni < 4; ++ni) {
      int m = m0 + wm * 128 + mi * 16 + lk * 4;
      int n = n0 + wn * 64 + ni * 16 + lrow;
      float* cp = &C[(size_t)m * OUT_DIM + n];
#pragma unroll
      for (int r = 0; r < 4; ++r) cp[(size_t)r * OUT_DIM] = acc[mi][ni][r];
    }
}

// ---------------- launch ----------------

extern "C" void kernel_launch(void* const* d_in, const int* in_sizes, int n_in,
                              void* d_out, int out_size, void* d_ws, size_t ws_size,
                              hipStream_t stream) {
  const float* x      = (const float*)d_in[0];
  const int*   packed = (const int*)d_in[1];
  const float* scales = (const float*)d_in[2];
  const float* vals   = (const float*)d_in[3];
  const int*   rows   = (const int*)d_in[4];
  const int*   cols   = (const int*)d_in[5];
  float* out = (float*)d_out;

  const int nnz = in_sizes[3];

  // ws: [0,32MB) W bf16 | [32,64MB) X bf16 | [64,128MB) fp32 outlier delta
  char* ws = (char*)d_ws;
  const size_t MB = 1024 * 1024;
  unsigned short* Wb = (unsigned short*)ws;
  unsigned short* Xb = (unsigned short*)(ws + 32 * MB);
  float*          Dl = (float*)(ws + 64 * MB);

  hipMemsetAsync(Dl, 0, 64 * MB, stream);
  scatter_kernel<<<(nnz + 255) / 256, 256, 0, stream>>>(vals, rows, cols, Dl, nnz);
  dequant_fused_kernel<<<8192, 256, 0, stream>>>(packed, scales, Dl, Wb);
  cvt_kernel<<<8192, 256, 0, stream>>>(x, Xb);
  gemm_kernel<<<256, 512, 0, stream>>>(Xb, Wb, out);
}

// Round 3
// 212.716 us; speedup vs baseline: 1.3457x; 1.0452x over previous
//
#include <hip/hip_runtime.h>
#include <cstdint>
#include <cstddef>

typedef __bf16 bf16x8 __attribute__((ext_vector_type(8)));
typedef float f32x4 __attribute__((ext_vector_type(4)));
typedef unsigned short ushort8 __attribute__((ext_vector_type(8)));

#define OUT_DIM 4096
#define IN_DIM 4096
#define NT 64  // K tiles of 64

// ---------------- helpers ----------------

__device__ __forceinline__ unsigned short f2bf(float f) {
  unsigned u = __float_as_uint(f);
  return (unsigned short)((u + 0x7FFFu + ((u >> 16) & 1u)) >> 16);
}

__device__ __forceinline__ void async_copy16(const void* g, void* l) {
  __builtin_amdgcn_global_load_lds(
      (const __attribute__((address_space(1))) unsigned int*)g,
      (__attribute__((address_space(3))) unsigned int*)l, 16, 0, 0);
}

// ---------------- weight build ----------------

__global__ __launch_bounds__(256) void scatter_kernel(
    const float* __restrict__ vals, const int* __restrict__ rows,
    const int* __restrict__ cols, float* __restrict__ delta, int nnz) {
  int i = blockIdx.x * 256 + threadIdx.x;
  if (i < nnz) {
    atomicAdd(&delta[(size_t)rows[i] * IN_DIM + cols[i]], vals[i]);
  }
}

// fused: int4 dequant + outlier delta add + round to bf16. 8 weights/thread.
__global__ __launch_bounds__(256) void dequant_fused_kernel(
    const int* __restrict__ packed, const float* __restrict__ scales,
    const float* __restrict__ delta, unsigned short* __restrict__ wb) {
  int idx = blockIdx.x * 256 + threadIdx.x;  // 4 packed int32 bytes -> 8 weights
  int4 p = reinterpret_cast<const int4*>(packed)[idx];
  float s = scales[idx >> 9];  // 512 int4-groups per row
  float4 d0 = reinterpret_cast<const float4*>(delta)[idx * 2];
  float4 d1 = reinterpret_cast<const float4*>(delta)[idx * 2 + 1];
  ushort8 o;
  o[0] = f2bf((float)((p.x & 15) - 8) * s + d0.x);
  o[1] = f2bf((float)(((p.x >> 4) & 15) - 8) * s + d0.y);
  o[2] = f2bf((float)((p.y & 15) - 8) * s + d0.z);
  o[3] = f2bf((float)(((p.y >> 4) & 15) - 8) * s + d0.w);
  o[4] = f2bf((float)((p.z & 15) - 8) * s + d1.x);
  o[5] = f2bf((float)(((p.z >> 4) & 15) - 8) * s + d1.y);
  o[6] = f2bf((float)((p.w & 15) - 8) * s + d1.z);
  o[7] = f2bf((float)(((p.w >> 4) & 15) - 8) * s + d1.w);
  *reinterpret_cast<ushort8*>(&wb[(size_t)idx * 8]) = o;
}

__global__ __launch_bounds__(256) void cvt_kernel(
    const float* __restrict__ in, unsigned short* __restrict__ out) {
  int i = blockIdx.x * 256 + threadIdx.x;
  float4 a = reinterpret_cast<const float4*>(in)[2 * i];
  float4 b = reinterpret_cast<const float4*>(in)[2 * i + 1];
  ushort8 o;
  o[0] = f2bf(a.x); o[1] = f2bf(a.y); o[2] = f2bf(a.z); o[3] = f2bf(a.w);
  o[4] = f2bf(b.x); o[5] = f2bf(b.y); o[6] = f2bf(b.z); o[7] = f2bf(b.w);
  *reinterpret_cast<ushort8*>(&out[(size_t)i * 8]) = o;
}

// ---------------- GEMM: C[N][O] = A[N][K] * B[O][K]^T, 256x256 tile, -------
// 8 waves, deep pipeline: k-half-major slabs, counted vmcnt, setprio,
// and a both-sides XOR bank swizzle (rule #21).
//
// Slab = [256 rows][32 k] bf16 = 16KB; 8 slabs: [buf][op(A/B)][kh].
// Swizzle: logical (row, slot) lives at physical slot^sigma(row),
// sigma(row) = (row>>1)&3 (16B granularity). DMA dest stays linear;
// the global SOURCE slot is pre-swizzled (sigma(r0+128)==sigma(r0), so
// both row-chunks share one pointer); reads fold sigma into lk. After
// swizzle every 8 consecutive lanes of a frag ds_read_b128 cover all 32
// banks exactly once.
//
// Pipeline ledger (tile t in buf t%2): P1(mh0,ks0) issues A1(t+1)->buf^1;
// P2(mh1,ks0) issues B1(t+1)->buf^1, vmcnt(8); P3(mh0,ks1) issues
// A0(t+2)->buf; P4(mh1,ks1) issues B0(t+2)->buf, vmcnt(8). Every issue
// targets a slot whose last ds_read finished before a prior barrier; every
// ds_read is covered by a prior vmcnt(8)+barrier.

#define SLABOFF(buf, op, kh) ((((buf) * 4) + ((op) * 2) + (kh)) * 8192)

#define STAGE(buf, op, kh, kt)                                              \
  do {                                                                      \
    const unsigned short* g_ = ((op) ? gB : gA) + (kt) * 64 + (kh) * 32;    \
    unsigned short* l_ = (unsigned short*)lds + SLABOFF(buf, op, kh) + wave * 512; \
    async_copy16(g_, l_);                                                   \
    async_copy16(g_ + 128 * IN_DIM, l_ + 4096);                             \
  } while (0)

#define MFMA_ __builtin_amdgcn_mfma_f32_16x16x32_bf16

#define PHASE(BUF, KS, MH, READB, STAGEST, DOWAIT)                          \
  do {                                                                      \
    const unsigned short* as_ = (const unsigned short*)lds + SLABOFF(BUF, 0, KS); \
    bf16x8 a0_ = *(const bf16x8*)(as_ + offA[(MH) * 4 + 0]);                \
    bf16x8 a1_ = *(const bf16x8*)(as_ + offA[(MH) * 4 + 1]);                \
    bf16x8 a2_ = *(const bf16x8*)(as_ + offA[(MH) * 4 + 2]);                \
    bf16x8 a3_ = *(const bf16x8*)(as_ + offA[(MH) * 4 + 3]);                \
    if (READB) {                                                            \
      const unsigned short* bs_ = (const unsigned short*)lds + SLABOFF(BUF, 1, KS); \
      bB0 = *(const bf16x8*)(bs_ + offB[0]);                                \
      bB1 = *(const bf16x8*)(bs_ + offB[1]);                                \
      bB2 = *(const bf16x8*)(bs_ + offB[2]);                                \
      bB3 = *(const bf16x8*)(bs_ + offB[3]);                                \
    }                                                                       \
    STAGEST;                                                                \
    if (DOWAIT) asm volatile("s_waitcnt vmcnt(8)" ::: "memory");            \
    __builtin_amdgcn_s_barrier();                                           \
    asm volatile("s_waitcnt lgkmcnt(0)" ::: "memory");                      \
    __builtin_amdgcn_sched_barrier(0);                                      \
    __builtin_amdgcn_s_setprio(1);                                          \
    acc[(MH) * 4 + 0][0] = MFMA_(a0_, bB0, acc[(MH) * 4 + 0][0], 0, 0, 0);  \
    acc[(MH) * 4 + 0][1] = MFMA_(a0_, bB1, acc[(MH) * 4 + 0][1], 0, 0, 0);  \
    acc[(MH) * 4 + 0][2] = MFMA_(a0_, bB2, acc[(MH) * 4 + 0][2], 0, 0, 0);  \
    acc[(MH) * 4 + 0][3] = MFMA_(a0_, bB3, acc[(MH) * 4 + 0][3], 0, 0, 0);  \
    acc[(MH) * 4 + 1][0] = MFMA_(a1_, bB0, acc[(MH) * 4 + 1][0], 0, 0, 0);  \
    acc[(MH) * 4 + 1][1] = MFMA_(a1_, bB1, acc[(MH) * 4 + 1][1], 0, 0, 0);  \
    acc[(MH) * 4 + 1][2] = MFMA_(a1_, bB2, acc[(MH) * 4 + 1][2], 0, 0, 0);  \
    acc[(MH) * 4 + 1][3] = MFMA_(a1_, bB3, acc[(MH) * 4 + 1][3], 0, 0, 0);  \
    acc[(MH) * 4 + 2][0] = MFMA_(a2_, bB0, acc[(MH) * 4 + 2][0], 0, 0, 0);  \
    acc[(MH) * 4 + 2][1] = MFMA_(a2_, bB1, acc[(MH) * 4 + 2][1], 0, 0, 0);  \
    acc[(MH) * 4 + 2][2] = MFMA_(a2_, bB2, acc[(MH) * 4 + 2][2], 0, 0, 0);  \
    acc[(MH) * 4 + 2][3] = MFMA_(a2_, bB3, acc[(MH) * 4 + 2][3], 0, 0, 0);  \
    acc[(MH) * 4 + 3][0] = MFMA_(a3_, bB0, acc[(MH) * 4 + 3][0], 0, 0, 0);  \
    acc[(MH) * 4 + 3][1] = MFMA_(a3_, bB1, acc[(MH) * 4 + 3][1], 0, 0, 0);  \
    acc[(MH) * 4 + 3][2] = MFMA_(a3_, bB2, acc[(MH) * 4 + 3][2], 0, 0, 0);  \
    acc[(MH) * 4 + 3][3] = MFMA_(a3_, bB3, acc[(MH) * 4 + 3][3], 0, 0, 0);  \
    __builtin_amdgcn_s_setprio(0);                                          \
    __builtin_amdgcn_s_barrier();                                           \
  } while (0)

#define MINC(x) ((x) < NT ? (x) : (NT - 1))

#define TILE(BUF, t)                                                        \
  do {                                                                      \
    PHASE(BUF, 0, 0, true, STAGE(1 - (BUF), 0, 1, MINC((t) + 1)), false);   \
    PHASE(BUF, 0, 1, false, STAGE(1 - (BUF), 1, 1, MINC((t) + 1)), true);   \
    PHASE(BUF, 1, 0, true, STAGE(BUF, 0, 0, MINC((t) + 2)), false);         \
    PHASE(BUF, 1, 1, false, STAGE(BUF, 1, 0, MINC((t) + 2)), true);         \
  } while (0)

__global__ __launch_bounds__(512, 2) void gemm_kernel(
    const unsigned short* __restrict__ A,  // [4096][4096] bf16 (x)
    const unsigned short* __restrict__ B,  // [4096][4096] bf16 (W)
    float* __restrict__ C) {               // [4096][4096] fp32
  __shared__ __align__(16) unsigned short lds[65536];  // 128 KiB

  // 4x8 (bm x bn) super-tile per XCD for L2 locality; 256%8==0 -> bijective
  const int bid = blockIdx.x;
  const int xcd = bid & 7, i_ = bid >> 3;
  const int bm = (xcd >> 1) * 4 + (i_ >> 3);
  const int bn = (xcd & 1) * 8 + (i_ & 7);
  const int m0 = bm * 256, n0 = bn * 256;

  const int tid = threadIdx.x;
  const int wave = tid >> 6, lane = tid & 63;
  const int wm = wave >> 2, wn = wave & 3;  // 2M x 4N wave grid
  const int lrow = lane & 15, lk = lane >> 4;

  // staging: chunk0 = tid -> (row=tid>>2, phys slot=tid&3); chunk1 = +128 rows.
  // SOURCE slot pre-swizzled so swizzled-read sees correct data (rule #21).
  const int r0 = tid >> 2, s0 = tid & 3;
  const int s0s = s0 ^ ((r0 >> 1) & 3);
  const unsigned short* gA = A + (size_t)(m0 + r0) * IN_DIM + s0s * 8;
  const unsigned short* gB = B + (size_t)(n0 + r0) * IN_DIM + s0s * 8;

  // frag read offsets (ushort units) within a [256][32] slab, sigma folded in
  const int lks = lk ^ ((lrow >> 1) & 3);
  int offA[8], offB[4];
#pragma unroll
  for (int i = 0; i < 8; ++i) offA[i] = (wm * 128 + i * 16 + lrow) * 32 + lks * 8;
#pragma unroll
  for (int i = 0; i < 4; ++i) offB[i] = (wn * 64 + i * 16 + lrow) * 32 + lks * 8;

  f32x4 acc[8][4];
#pragma unroll
  for (int mi = 0; mi < 8; ++mi)
#pragma unroll
    for (int ni = 0; ni < 4; ++ni) acc[mi][ni] = (f32x4){0.f, 0.f, 0.f, 0.f};

  // prologue: A0(0) B0(0) A1(0) B1(0) -> buf0; A0(1) B0(1) -> buf1.
  // empty-asm separators pin issue order (vmcnt counts issue order).
  STAGE(0, 0, 0, 0); STAGE(0, 1, 0, 0);
  asm volatile("" ::: "memory");
  STAGE(0, 0, 1, 0); STAGE(0, 1, 1, 0);
  asm volatile("" ::: "memory");
  STAGE(1, 0, 0, 1); STAGE(1, 1, 0, 1);
  asm volatile("s_waitcnt vmcnt(8)" ::: "memory");  // A0(0),B0(0) complete
  __builtin_amdgcn_s_barrier();

  bf16x8 bB0, bB1, bB2, bB3;
#pragma unroll 1
  for (int p = 0; p < NT / 2; ++p) {
    const int te = 2 * p;
    TILE(0, te);
    TILE(1, te + 1);
  }
  asm volatile("s_waitcnt vmcnt(0)" ::: "memory");  // drain DMA before endpgm

  // epilogue: D mapping col=lane&15, row=(lane>>4)*4+reg
#pragma unroll
  for (int mi = 0; mi < 8; ++mi)
#pragma unroll
    for (int ni = 0; ni < 4; ++ni) {
      int m = m0 + wm * 128 + mi * 16 + lk * 4;
      int n = n0 + wn * 64 + ni * 16 + lrow;
      float* cp = &C[(size_t)m * OUT_DIM + n];
#pragma unroll
      for (int r = 0; r < 4; ++r) cp[(size_t)r * OUT_DIM] = acc[mi][ni][r];
    }
}

// ---------------- launch ----------------

extern "C" void kernel_launch(void* const* d_in, const int* in_sizes, int n_in,
                              void* d_out, int out_size, void* d_ws, size_t ws_size,
                              hipStream_t stream) {
  const float* x      = (const float*)d_in[0];
  const int*   packed = (const int*)d_in[1];
  const float* scales = (const float*)d_in[2];
  const float* vals   = (const float*)d_in[3];
  const int*   rows   = (const int*)d_in[4];
  const int*   cols   = (const int*)d_in[5];
  float* out = (float*)d_out;

  const int nnz = in_sizes[3];

  // ws: [0,32MB) W bf16 | [32,64MB) X bf16 | [64,128MB) fp32 outlier delta
  char* ws = (char*)d_ws;
  const size_t MB = 1024 * 1024;
  unsigned short* Wb = (unsigned short*)ws;
  unsigned short* Xb = (unsigned short*)(ws + 32 * MB);
  float*          Dl = (float*)(ws + 64 * MB);

  hipMemsetAsync(Dl, 0, 64 * MB, stream);
  scatter_kernel<<<(nnz + 255) / 256, 256, 0, stream>>>(vals, rows, cols, Dl, nnz);
  dequant_fused_kernel<<<8192, 256, 0, stream>>>(packed, scales, Dl, Wb);
  cvt_kernel<<<8192, 256, 0, stream>>>(x, Xb);
  gemm_kernel<<<256, 512, 0, stream>>>(Xb, Wb, out);
}

// Round 5
// 187.815 us; speedup vs baseline: 1.5241x; 1.1326x over previous
//
#include <hip/hip_runtime.h>
#include <cstdint>
#include <cstddef>

typedef __bf16 bf16x8 __attribute__((ext_vector_type(8)));
typedef float f32x4 __attribute__((ext_vector_type(4)));
typedef unsigned short ushort8 __attribute__((ext_vector_type(8)));

#define OUT_DIM 4096
#define IN_DIM 4096
#define NT 64  // K tiles of 64

// ---------------- helpers ----------------

__device__ __forceinline__ unsigned short f2bf(float f) {
  unsigned u = __float_as_uint(f);
  return (unsigned short)((u + 0x7FFFu + ((u >> 16) & 1u)) >> 16);
}

__device__ __forceinline__ void async_copy16(const void* g, void* l) {
  __builtin_amdgcn_global_load_lds(
      (const __attribute__((address_space(1))) unsigned int*)g,
      (__attribute__((address_space(3))) unsigned int*)l, 16, 0, 0);
}

// ---------------- weight build ----------------

// int4 dequant -> bf16 Wb directly. 8 weights/thread, 64 MB total traffic.
__global__ __launch_bounds__(256) void dequant_kernel(
    const int* __restrict__ packed, const float* __restrict__ scales,
    unsigned short* __restrict__ wb) {
  int idx = blockIdx.x * 256 + threadIdx.x;  // 4 packed int32 bytes -> 8 weights
  int4 p = reinterpret_cast<const int4*>(packed)[idx];
  float s = scales[idx >> 9];  // 512 int4-groups per row
  ushort8 o;
  o[0] = f2bf((float)((p.x & 15) - 8) * s);
  o[1] = f2bf((float)(((p.x >> 4) & 15) - 8) * s);
  o[2] = f2bf((float)((p.y & 15) - 8) * s);
  o[3] = f2bf((float)(((p.y >> 4) & 15) - 8) * s);
  o[4] = f2bf((float)((p.z & 15) - 8) * s);
  o[5] = f2bf((float)(((p.z >> 4) & 15) - 8) * s);
  o[6] = f2bf((float)((p.w & 15) - 8) * s);
  o[7] = f2bf((float)(((p.w >> 4) & 15) - 8) * s);
  *reinterpret_cast<ushort8*>(&wb[(size_t)idx * 8]) = o;
}

// outlier add directly into bf16 weights via 32-bit CAS on the containing
// word. Duplicated (row,col) pairs each retry-accumulate correctly.
__global__ __launch_bounds__(256) void scatter_bf16_kernel(
    const float* __restrict__ vals, const int* __restrict__ rows,
    const int* __restrict__ cols, unsigned short* __restrict__ wb, int nnz) {
  int i = blockIdx.x * 256 + threadIdx.x;
  if (i >= nnz) return;
  size_t idx = (size_t)rows[i] * IN_DIM + cols[i];
  unsigned int* word = (unsigned int*)(wb + (idx & ~(size_t)1));
  const bool hi = (idx & 1) != 0;
  const float v = vals[i];
  unsigned int old = *word, assumed;
  do {
    assumed = old;
    unsigned short h = hi ? (unsigned short)(assumed >> 16)
                          : (unsigned short)(assumed & 0xFFFFu);
    float f = __uint_as_float((unsigned)h << 16);  // bf16 -> f32 exact
    unsigned short nh = f2bf(f + v);
    unsigned int nw = hi ? ((assumed & 0x0000FFFFu) | ((unsigned)nh << 16))
                         : ((assumed & 0xFFFF0000u) | (unsigned)nh);
    old = atomicCAS(word, assumed, nw);
  } while (old != assumed);
}

__global__ __launch_bounds__(256) void cvt_kernel(
    const float* __restrict__ in, unsigned short* __restrict__ out) {
  int i = blockIdx.x * 256 + threadIdx.x;
  float4 a = reinterpret_cast<const float4*>(in)[2 * i];
  float4 b = reinterpret_cast<const float4*>(in)[2 * i + 1];
  ushort8 o;
  o[0] = f2bf(a.x); o[1] = f2bf(a.y); o[2] = f2bf(a.z); o[3] = f2bf(a.w);
  o[4] = f2bf(b.x); o[5] = f2bf(b.y); o[6] = f2bf(b.z); o[7] = f2bf(b.w);
  *reinterpret_cast<ushort8*>(&out[(size_t)i * 8]) = o;
}

// ---------------- GEMM: C[N][O] = A[N][K] * B[O][K]^T, 256x256 tile, -------
// 8 waves, deep pipeline: k-half-major slabs, counted vmcnt, setprio,
// and a both-sides XOR bank swizzle (rule #21). Identical to round 3's
// verified kernel (124 us, MfmaUtil 50%, bank conflicts 0) — round 4's
// acc[(MH)*2+2] typo restored to acc[(MH)*4+2].
//
// Slab = [256 rows][32 k] bf16 = 16KB; 8 slabs: [buf][op(A/B)][kh].
// Swizzle: logical (row, slot) lives at physical slot^sigma(row),
// sigma(row) = (row>>1)&3 (16B granularity). DMA dest stays linear;
// the global SOURCE slot is pre-swizzled (sigma(r0+128)==sigma(r0), so
// both row-chunks share one pointer); reads fold sigma into lk.
//
// Pipeline ledger (tile t in buf t%2): P1(mh0,ks0) issues A1(t+1)->buf^1;
// P2(mh1,ks0) issues B1(t+1)->buf^1, vmcnt(8); P3(mh0,ks1) issues
// A0(t+2)->buf; P4(mh1,ks1) issues B0(t+2)->buf, vmcnt(8). Every issue
// targets a slot whose last ds_read finished before a prior barrier; every
// ds_read is covered by a prior vmcnt(8)+barrier.

#define SLABOFF(buf, op, kh) ((((buf) * 4) + ((op) * 2) + (kh)) * 8192)

#define STAGE(buf, op, kh, kt)                                              \
  do {                                                                      \
    const unsigned short* g_ = ((op) ? gB : gA) + (kt) * 64 + (kh) * 32;    \
    unsigned short* l_ = (unsigned short*)lds + SLABOFF(buf, op, kh) + wave * 512; \
    async_copy16(g_, l_);                                                   \
    async_copy16(g_ + 128 * IN_DIM, l_ + 4096);                             \
  } while (0)

#define MFMA_ __builtin_amdgcn_mfma_f32_16x16x32_bf16

#define PHASE(BUF, KS, MH, READB, STAGEST, DOWAIT)                          \
  do {                                                                      \
    const unsigned short* as_ = (const unsigned short*)lds + SLABOFF(BUF, 0, KS); \
    bf16x8 a0_ = *(const bf16x8*)(as_ + offA[(MH) * 4 + 0]);                \
    bf16x8 a1_ = *(const bf16x8*)(as_ + offA[(MH) * 4 + 1]);                \
    bf16x8 a2_ = *(const bf16x8*)(as_ + offA[(MH) * 4 + 2]);                \
    bf16x8 a3_ = *(const bf16x8*)(as_ + offA[(MH) * 4 + 3]);                \
    if (READB) {                                                            \
      const unsigned short* bs_ = (const unsigned short*)lds + SLABOFF(BUF, 1, KS); \
      bB0 = *(const bf16x8*)(bs_ + offB[0]);                                \
      bB1 = *(const bf16x8*)(bs_ + offB[1]);                                \
      bB2 = *(const bf16x8*)(bs_ + offB[2]);                                \
      bB3 = *(const bf16x8*)(bs_ + offB[3]);                                \
    }                                                                       \
    STAGEST;                                                                \
    if (DOWAIT) asm volatile("s_waitcnt vmcnt(8)" ::: "memory");            \
    __builtin_amdgcn_s_barrier();                                           \
    asm volatile("s_waitcnt lgkmcnt(0)" ::: "memory");                      \
    __builtin_amdgcn_sched_barrier(0);                                      \
    __builtin_amdgcn_s_setprio(1);                                          \
    acc[(MH) * 4 + 0][0] = MFMA_(a0_, bB0, acc[(MH) * 4 + 0][0], 0, 0, 0);  \
    acc[(MH) * 4 + 0][1] = MFMA_(a0_, bB1, acc[(MH) * 4 + 0][1], 0, 0, 0);  \
    acc[(MH) * 4 + 0][2] = MFMA_(a0_, bB2, acc[(MH) * 4 + 0][2], 0, 0, 0);  \
    acc[(MH) * 4 + 0][3] = MFMA_(a0_, bB3, acc[(MH) * 4 + 0][3], 0, 0, 0);  \
    acc[(MH) * 4 + 1][0] = MFMA_(a1_, bB0, acc[(MH) * 4 + 1][0], 0, 0, 0);  \
    acc[(MH) * 4 + 1][1] = MFMA_(a1_, bB1, acc[(MH) * 4 + 1][1], 0, 0, 0);  \
    acc[(MH) * 4 + 1][2] = MFMA_(a1_, bB2, acc[(MH) * 4 + 1][2], 0, 0, 0);  \
    acc[(MH) * 4 + 1][3] = MFMA_(a1_, bB3, acc[(MH) * 4 + 1][3], 0, 0, 0);  \
    acc[(MH) * 4 + 2][0] = MFMA_(a2_, bB0, acc[(MH) * 4 + 2][0], 0, 0, 0);  \
    acc[(MH) * 4 + 2][1] = MFMA_(a2_, bB1, acc[(MH) * 4 + 2][1], 0, 0, 0);  \
    acc[(MH) * 4 + 2][2] = MFMA_(a2_, bB2, acc[(MH) * 4 + 2][2], 0, 0, 0);  \
    acc[(MH) * 4 + 2][3] = MFMA_(a2_, bB3, acc[(MH) * 4 + 2][3], 0, 0, 0);  \
    acc[(MH) * 4 + 3][0] = MFMA_(a3_, bB0, acc[(MH) * 4 + 3][0], 0, 0, 0);  \
    acc[(MH) * 4 + 3][1] = MFMA_(a3_, bB1, acc[(MH) * 4 + 3][1], 0, 0, 0);  \
    acc[(MH) * 4 + 3][2] = MFMA_(a3_, bB2, acc[(MH) * 4 + 3][2], 0, 0, 0);  \
    acc[(MH) * 4 + 3][3] = MFMA_(a3_, bB3, acc[(MH) * 4 + 3][3], 0, 0, 0);  \
    __builtin_amdgcn_s_setprio(0);                                          \
    __builtin_amdgcn_s_barrier();                                           \
  } while (0)

#define MINC(x) ((x) < NT ? (x) : (NT - 1))

#define TILE(BUF, t)                                                        \
  do {                                                                      \
    PHASE(BUF, 0, 0, true, STAGE(1 - (BUF), 0, 1, MINC((t) + 1)), false);   \
    PHASE(BUF, 0, 1, false, STAGE(1 - (BUF), 1, 1, MINC((t) + 1)), true);   \
    PHASE(BUF, 1, 0, true, STAGE(BUF, 0, 0, MINC((t) + 2)), false);         \
    PHASE(BUF, 1, 1, false, STAGE(BUF, 1, 0, MINC((t) + 2)), true);         \
  } while (0)

__global__ __launch_bounds__(512, 2) void gemm_kernel(
    const unsigned short* __restrict__ A,  // [4096][4096] bf16 (x)
    const unsigned short* __restrict__ B,  // [4096][4096] bf16 (W)
    float* __restrict__ C) {               // [4096][4096] fp32
  __shared__ __align__(16) unsigned short lds[65536];  // 128 KiB

  // 4x8 (bm x bn) super-tile per XCD for L2 locality; 256%8==0 -> bijective
  const int bid = blockIdx.x;
  const int xcd = bid & 7, i_ = bid >> 3;
  const int bm = (xcd >> 1) * 4 + (i_ >> 3);
  const int bn = (xcd & 1) * 8 + (i_ & 7);
  const int m0 = bm * 256, n0 = bn * 256;

  const int tid = threadIdx.x;
  const int wave = tid >> 6, lane = tid & 63;
  const int wm = wave >> 2, wn = wave & 3;  // 2M x 4N wave grid
  const int lrow = lane & 15, lk = lane >> 4;

  // staging: chunk0 = tid -> (row=tid>>2, phys slot=tid&3); chunk1 = +128 rows.
  // SOURCE slot pre-swizzled so swizzled-read sees correct data (rule #21).
  const int r0 = tid >> 2, s0 = tid & 3;
  const int s0s = s0 ^ ((r0 >> 1) & 3);
  const unsigned short* gA = A + (size_t)(m0 + r0) * IN_DIM + s0s * 8;
  const unsigned short* gB = B + (size_t)(n0 + r0) * IN_DIM + s0s * 8;

  // frag read offsets (ushort units) within a [256][32] slab, sigma folded in
  const int lks = lk ^ ((lrow >> 1) & 3);
  int offA[8], offB[4];
#pragma unroll
  for (int i = 0; i < 8; ++i) offA[i] = (wm * 128 + i * 16 + lrow) * 32 + lks * 8;
#pragma unroll
  for (int i = 0; i < 4; ++i) offB[i] = (wn * 64 + i * 16 + lrow) * 32 + lks * 8;

  f32x4 acc[8][4];
#pragma unroll
  for (int mi = 0; mi < 8; ++mi)
#pragma unroll
    for (int ni = 0; ni < 4; ++ni) acc[mi][ni] = (f32x4){0.f, 0.f, 0.f, 0.f};

  // prologue: A0(0) B0(0) A1(0) B1(0) -> buf0; A0(1) B0(1) -> buf1.
  // empty-asm separators pin issue order (vmcnt counts issue order).
  STAGE(0, 0, 0, 0); STAGE(0, 1, 0, 0);
  asm volatile("" ::: "memory");
  STAGE(0, 0, 1, 0); STAGE(0, 1, 1, 0);
  asm volatile("" ::: "memory");
  STAGE(1, 0, 0, 1); STAGE(1, 1, 0, 1);
  asm volatile("s_waitcnt vmcnt(8)" ::: "memory");  // A0(0),B0(0) complete
  __builtin_amdgcn_s_barrier();

  bf16x8 bB0, bB1, bB2, bB3;
#pragma unroll 1
  for (int p = 0; p < NT / 2; ++p) {
    const int te = 2 * p;
    TILE(0, te);
    TILE(1, te + 1);
  }
  asm volatile("s_waitcnt vmcnt(0)" ::: "memory");  // drain DMA before endpgm

  // epilogue: D mapping col=lane&15, row=(lane>>4)*4+reg
#pragma unroll
  for (int mi = 0; mi < 8; ++mi)
#pragma unroll
    for (int ni = 0; ni < 4; ++ni) {
      int m = m0 + wm * 128 + mi * 16 + lk * 4;
      int n = n0 + wn * 64 + ni * 16 + lrow;
      float* cp = &C[(size_t)m * OUT_DIM + n];
#pragma unroll
      for (int r = 0; r < 4; ++r) cp[(size_t)r * OUT_DIM] = acc[mi][ni][r];
    }
}

// ---------------- launch ----------------

extern "C" void kernel_launch(void* const* d_in, const int* in_sizes, int n_in,
                              void* d_out, int out_size, void* d_ws, size_t ws_size,
                              hipStream_t stream) {
  const float* x      = (const float*)d_in[0];
  const int*   packed = (const int*)d_in[1];
  const float* scales = (const float*)d_in[2];
  const float* vals   = (const float*)d_in[3];
  const int*   rows   = (const int*)d_in[4];
  const int*   cols   = (const int*)d_in[5];
  float* out = (float*)d_out;

  const int nnz = in_sizes[3];

  // ws: [0,32MB) W bf16 | [32,64MB) X bf16
  char* ws = (char*)d_ws;
  const size_t MB = 1024 * 1024;
  unsigned short* Wb = (unsigned short*)ws;
  unsigned short* Xb = (unsigned short*)(ws + 32 * MB);

  // 1) int4 dequant -> bf16 Wb (no fp32 intermediate, no memset)
  dequant_kernel<<<8192, 256, 0, stream>>>(packed, scales, Wb);
  // 2) outlier residual added in-place via 32-bit CAS (duplicates safe)
  scatter_bf16_kernel<<<(nnz + 255) / 256, 256, 0, stream>>>(vals, rows, cols, Wb, nnz);
  // 3) x fp32 -> bf16
  cvt_kernel<<<8192, 256, 0, stream>>>(x, Xb);
  // 4) bf16 MFMA GEMM: out = Xb (4096x4096) * Wb^T
  gemm_kernel<<<256, 512, 0, stream>>>(Xb, Wb, out);
}